// Round 10
// baseline (103.313 us; speedup 1.0000x reference)
//
#include <hip/hip_runtime.h>
#include <math.h>

#define PP 9       // K*K
#define CAPS 32
#define PS 16
#define OH 15
#define HH 32
#define WW 32
#define LN_2PI 1.8378770664093453f

typedef float f32x2 __attribute__((ext_vector_type(2)));
typedef _Float16 f16x2 __attribute__((ext_vector_type(2)));

__device__ __forceinline__ float frcp(float x) {
    float r;
    asm("v_rcp_f32 %0, %1" : "=v"(r) : "v"(x));
    return r;
}
__device__ __forceinline__ f32x2 splat2(float x) {
    f32x2 r; r.x = x; r.y = x; return r;
}
__device__ __forceinline__ f32x2 pkfma(f32x2 a, f32x2 b, f32x2 c) {
    return __builtin_elementwise_fma(a, b, c);  // -> v_pk_fma_f32 (gfx950 packed fp32)
}

// fp16x2 compression of the vote tile. R0..R8 post-mortem: wall is invariant
// to traffic/busy/I$/cross-lane tweaks but tracks sites-in-flight (always 4:
// v[9][8] f32x2 = 144 regs -> ~256/thread true alloc -> 2 waves/SIMD). Packing
// votes to 16-bit (vb[9][8] = 72 regs) fits the thread in <=128 regs -> 4
// waves/SIMD = 8 sites in flight. R9 tried bf16: absmax 0.453 = 1.9x OVER the
// 0.234 threshold (7-bit mantissa too coarse once EM sharpens sigma). fp16
// RNE has 8x smaller rel err (2^-11) and votes are bounded (|v| << 65504):
// predicted absmax ~0.06. Pack = 2x v_cvt_f16_f32 (RNE) + pack; unpack =
// v_cvt_f32_f16 (+SDWA hi) — same op count as the bf16 bit-ops at use sites.
__device__ __forceinline__ f16x2 pk_f16(f32x2 v) {
    f16x2 h;
    h.x = (_Float16)v.x;   // RNE
    h.y = (_Float16)v.y;
    return h;
}
__device__ __forceinline__ f32x2 unpk(f16x2 h) {
    f32x2 r;
    r.x = (float)h.x;
    r.y = (float)h.y;
    return r;
}

// DPP helpers (VALU pipe): quad_perm xor1=0xB1, xor2=0x4E; row_ror:4=0x124, row_ror:8=0x128.
template <int CTRL>
__device__ __forceinline__ float dppf(float x) {
    int r = __builtin_amdgcn_update_dpp(0, __builtin_bit_cast(int, x), CTRL, 0xF, 0xF, true);
    return __builtin_bit_cast(float, r);
}
__device__ __forceinline__ float row_sum16(float x) {
    x += dppf<0xB1>(x);
    x += dppf<0x4E>(x);
    x += dppf<0x124>(x);
    x += dppf<0x128>(x);
    return x;
}
__device__ __forceinline__ float row_max16(float x) {
    x = fmaxf(x, dppf<0xB1>(x));
    x = fmaxf(x, dppf<0x4E>(x));
    x = fmaxf(x, dppf<0x124>(x));
    x = fmaxf(x, dppf<0x128>(x));
    return x;
}
// xor16 within each 32-lane group (and-mask 0x1F) -> halves (= the 2 sites)
// stay independent. PROVEN primitive. permlane16_swap failed twice (R5/R6:
// identical inputs coalesce to one register -> in-place rotation). Keep this.
__device__ __forceinline__ float swz_xor16(float x) {
    return __builtin_bit_cast(float,
        __builtin_amdgcn_ds_swizzle(__builtin_bit_cast(int, x), 0x401F));
}

// Layout: each 64-lane wave = TWO sites (32 lanes each), lane = s*32 + c;
// thread owns all 16 pose elems of capsule c of site s (softmax amortized
// over 2 sites — split-PS and split-K both measured worse). Pose math packed
// f32x2 (v_pk_fma_f32); E-step phase-batched; EM loop kept rolled.
__global__ __launch_bounds__(64, 4) void emcaps_kernel(
    const float* __restrict__ x,      // (32,32,32,32,16)
    const float* __restrict__ a,      // (32,32,32,32)
    const float* __restrict__ wgt,    // (9,32,4,4)
    const float* __restrict__ beta_u, // (32)
    const float* __restrict__ beta_a, // (32)
    float* __restrict__ out_mu,       // (32,15,15,32,16)
    float* __restrict__ out_a)        // (32,15,15,32)
{
    const int lane = threadIdx.x;   // 0..63
    const int s = lane >> 5;        // site within pair
    const int c = lane & 31;        // capsule

    const int site = blockIdx.x * 2 + s;
    const int j = site % OH;
    const int t2 = site / OH;
    const int i = t2 % OH;
    const int b = t2 / OH;
    const int h0 = 2 * i, w0 = 2 * j;

    f16x2 vb[PP][8];   // fp16x2 votes: pair m = pose elems (2m, 2m+1)
    float r[PP];

    // ---- phase 1+2 fused per k: load x -> votes -> pack to fp16 ----
    // (keeps the f32 working set ~40 regs so the 128-reg budget holds; the
    // compiler still prefetches 2-3 k ahead within the budget)
    #pragma unroll
    for (int k = 0; k < PP; ++k) {
        const int hh = h0 + k / 3, ww = w0 + k % 3;
        const size_t pix = (size_t)(b * HH + hh) * WW + ww;
        const float* xb = x + pix * (CAPS * PS) + c * PS;
        float xt[PS];
        *(float4*)&xt[0]  = *(const float4*)xb;
        *(float4*)&xt[4]  = *(const float4*)(xb + 4);
        *(float4*)&xt[8]  = *(const float4*)(xb + 8);
        *(float4*)&xt[12] = *(const float4*)(xb + 12);
        r[k] = a[pix * CAPS + c] * (1.f / 32.f);  // initial r (it0)

        float wl[PS];
        const float* wb = wgt + k * (CAPS * PS) + c * PS;
        *(float4*)&wl[0]  = *(const float4*)wb;
        *(float4*)&wl[4]  = *(const float4*)(wb + 4);
        *(float4*)&wl[8]  = *(const float4*)(wb + 8);
        *(float4*)&wl[12] = *(const float4*)(wb + 12);

        // vote[t] = sum_q xt[(t&12)+q] * wl[q*4+(t&3)]; pair m = (2m, 2m+1)
        #pragma unroll
        for (int m = 0; m < 8; ++m) {
            f32x2 acc = splat2(0.f);
            #pragma unroll
            for (int q = 0; q < 4; ++q) {
                f32x2 w2; w2.x = wl[q * 4 + ((2 * m) & 3)]; w2.y = wl[q * 4 + ((2 * m + 1) & 3)];
                acc = pkfma(splat2(xt[((2 * m) & 12) + q]), w2, acc);
            }
            vb[k][m] = pk_f16(acc);
        }
    }

    const float bu = beta_u[c];
    const float ba = beta_a[c];
    const float eps = 1e-6f;
    const float lam = 1e-3f;

    f32x2 mu2[8], is22[8];   // is22 = 1/(2*sigma^2)
    float aoc = 0.f;
    float slgfull = 0.f;
    float r_sum;

    #pragma unroll 1   // one copy of E+M in the binary; limits live-range blowup
    for (int it = 0; it < 3; ++it) {
        if (it > 0) {
            // ---- E-step: phase-batched across the 9 independent k-chains ----
            const float addc = __logf(aoc) - slgfull - 8.f * LN_2PI;
            float lnk[PP], red[PP];
            #pragma unroll
            for (int k = 0; k < PP; ++k) {          // phase A: ln-posteriors
                f32x2 s2 = splat2(0.f);
                #pragma unroll
                for (int m = 0; m < 8; ++m) {
                    f32x2 d = unpk(vb[k][m]) - mu2[m];
                    s2 = pkfma(d * d, is22[m], s2);
                }
                lnk[k] = addc - (s2.x + s2.y);
            }
            #pragma unroll
            for (int k = 0; k < PP; ++k) red[k] = row_max16(lnk[k]);   // B: DPP maxes
            #pragma unroll
            for (int k = 0; k < PP; ++k)                                // C: swizzles
                red[k] = fmaxf(red[k], swz_xor16(red[k]));
            #pragma unroll
            for (int k = 0; k < PP; ++k) lnk[k] = __expf(lnk[k] - red[k]); // D: exps
            #pragma unroll
            for (int k = 0; k < PP; ++k) red[k] = row_sum16(lnk[k]);   // E: DPP sums
            #pragma unroll
            for (int k = 0; k < PP; ++k)                                // F: swizzles
                red[k] += swz_xor16(red[k]);
            #pragma unroll
            for (int k = 0; k < PP; ++k) r[k] = lnk[k] * frcp(red[k]); // G: normalize
        }

        // ---- M-step: two-pass (numerically required; expanded quadratic
        //      forms rejected — catastrophic cancellation class) ----
        r_sum = 0.f;
        #pragma unroll
        for (int k = 0; k < PP; ++k) r_sum += r[k];
        const float invr = frcp(r_sum + eps);
        #pragma unroll
        for (int k = 0; k < PP; ++k) r[k] *= invr;   // coeff

        #pragma unroll
        for (int m = 0; m < 8; ++m) {
            f32x2 acc = splat2(0.f);
            #pragma unroll
            for (int k = 0; k < PP; ++k) acc = pkfma(splat2(r[k]), unpk(vb[k][m]), acc);
            mu2[m] = acc;
        }
        float slg = 0.f;
        #pragma unroll
        for (int m = 0; m < 8; ++m) {
            f32x2 acc = splat2(0.f);
            #pragma unroll
            for (int k = 0; k < PP; ++k) {
                f32x2 d = unpk(vb[k][m]) - mu2[m];
                acc = pkfma(splat2(r[k]) * d, d, acc);
            }
            f32x2 sg = acc + splat2(eps);
            is22[m].x = frcp(2.f * sg.x);
            is22[m].y = frcp(2.f * sg.y);
            slg += 0.5f * __logf(sg.x * sg.y);   // = 0.5*(log sx + log sy)
        }
        slgfull = slg;
        const float ch = r_sum * (16.f * bu + slgfull);
        aoc = frcp(1.f + __expf(-lam * (ba - ch)));
    }

    // ---- outputs: each thread stores its 16 mu's (64B) + its a ----
    float* ob = out_mu + (size_t)site * (CAPS * PS) + c * PS;
    *(float4*)(ob + 0)  = *(float4*)&mu2[0];
    *(float4*)(ob + 4)  = *(float4*)&mu2[2];
    *(float4*)(ob + 8)  = *(float4*)&mu2[4];
    *(float4*)(ob + 12) = *(float4*)&mu2[6];
    out_a[(size_t)site * CAPS + c] = aoc;
}

extern "C" void kernel_launch(void* const* d_in, const int* in_sizes, int n_in,
                              void* d_out, int out_size, void* d_ws, size_t ws_size,
                              hipStream_t stream) {
    const float* x      = (const float*)d_in[0];
    const float* a      = (const float*)d_in[1];
    const float* wgt    = (const float*)d_in[2];
    const float* beta_u = (const float*)d_in[3];
    const float* beta_a = (const float*)d_in[4];

    float* out_mu = (float*)d_out;
    float* out_a  = (float*)d_out + (size_t)32 * OH * OH * CAPS * PS;  // 3,686,400

    const int n_sites = 32 * OH * OH;  // 7200
    emcaps_kernel<<<n_sites / 2, 64, 0, stream>>>(x, a, wgt, beta_u, beta_a, out_mu, out_a);
}

// Round 11
// 72.135 us; speedup vs baseline: 1.4322x; 1.4322x over previous
//
#include <hip/hip_runtime.h>
#include <math.h>

#define PP 9       // K*K
#define CAPS 32
#define PS 16
#define OH 15
#define HH 32
#define WW 32
#define LN_2PI 1.8378770664093453f

typedef float f32x2 __attribute__((ext_vector_type(2)));
typedef _Float16 f16x2 __attribute__((ext_vector_type(2)));

__device__ __forceinline__ float frcp(float x) {
    float r;
    asm("v_rcp_f32 %0, %1" : "=v"(r) : "v"(x));
    return r;
}
__device__ __forceinline__ f32x2 splat2(float x) {
    f32x2 r; r.x = x; r.y = x; return r;
}
__device__ __forceinline__ f32x2 pkfma(f32x2 a, f32x2 b, f32x2 c) {
    return __builtin_elementwise_fma(a, b, c);  // -> v_pk_fma_f32 (gfx950 packed fp32)
}

// fp16x2 compression of the vote tile (accuracy PROVEN R10: absmax 0.0625 vs
// 0.234 threshold). Purpose: shrink per-thread state so more waves fit per
// SIMD — R0..R8 wall was invariant to traffic/busy/I$/cross-lane tweaks but
// always ran 4 sites-in-flight/SIMD (v[9][8] f32 = 144 regs -> ~256/thread).
// R10 lesson: the full thread needs ~140 regs; forcing the 128-reg cap of
// (64,4) SPILLED the vote tile to scratch (WRITE_SIZE 15->141 MB, 128us).
// This round: (64,3) -> 170-reg cap -> fits with margin -> 3 waves/SIMD =
// 6 sites in flight, NO spill. Clean test of the sites-in-flight model.
__device__ __forceinline__ f16x2 pk_f16(f32x2 v) {
    f16x2 h;
    h.x = (_Float16)v.x;   // RNE
    h.y = (_Float16)v.y;
    return h;
}
__device__ __forceinline__ f32x2 unpk(f16x2 h) {
    f32x2 r;
    r.x = (float)h.x;
    r.y = (float)h.y;
    return r;
}

// DPP helpers (VALU pipe): quad_perm xor1=0xB1, xor2=0x4E; row_ror:4=0x124, row_ror:8=0x128.
template <int CTRL>
__device__ __forceinline__ float dppf(float x) {
    int r = __builtin_amdgcn_update_dpp(0, __builtin_bit_cast(int, x), CTRL, 0xF, 0xF, true);
    return __builtin_bit_cast(float, r);
}
__device__ __forceinline__ float row_sum16(float x) {
    x += dppf<0xB1>(x);
    x += dppf<0x4E>(x);
    x += dppf<0x124>(x);
    x += dppf<0x128>(x);
    return x;
}
__device__ __forceinline__ float row_max16(float x) {
    x = fmaxf(x, dppf<0xB1>(x));
    x = fmaxf(x, dppf<0x4E>(x));
    x = fmaxf(x, dppf<0x124>(x));
    x = fmaxf(x, dppf<0x128>(x));
    return x;
}
// xor16 within each 32-lane group (and-mask 0x1F) -> halves (= the 2 sites)
// stay independent. PROVEN primitive. permlane16_swap failed twice (R5/R6:
// identical inputs coalesce to one register -> in-place rotation). Keep this.
__device__ __forceinline__ float swz_xor16(float x) {
    return __builtin_bit_cast(float,
        __builtin_amdgcn_ds_swizzle(__builtin_bit_cast(int, x), 0x401F));
}

// Layout: each 64-lane wave = TWO sites (32 lanes each), lane = s*32 + c;
// thread owns all 16 pose elems of capsule c of site s (softmax amortized
// over 2 sites — split-PS and split-K both measured worse). Pose math packed
// f32x2 (v_pk_fma_f32); E-step phase-batched; EM loop kept rolled.
__global__ __launch_bounds__(64, 3) void emcaps_kernel(
    const float* __restrict__ x,      // (32,32,32,32,16)
    const float* __restrict__ a,      // (32,32,32,32)
    const float* __restrict__ wgt,    // (9,32,4,4)
    const float* __restrict__ beta_u, // (32)
    const float* __restrict__ beta_a, // (32)
    float* __restrict__ out_mu,       // (32,15,15,32,16)
    float* __restrict__ out_a)        // (32,15,15,32)
{
    const int lane = threadIdx.x;   // 0..63
    const int s = lane >> 5;        // site within pair
    const int c = lane & 31;        // capsule

    const int site = blockIdx.x * 2 + s;
    const int j = site % OH;
    const int t2 = site / OH;
    const int i = t2 % OH;
    const int b = t2 / OH;
    const int h0 = 2 * i, w0 = 2 * j;

    f16x2 vb[PP][8];   // fp16x2 votes: pair m = pose elems (2m, 2m+1)
    float r[PP];

    // ---- phase 1+2 fused per k: load x -> votes -> pack to fp16 ----
    // (keeps the f32 working set ~40 regs; compiler prefetches ahead in-budget)
    #pragma unroll
    for (int k = 0; k < PP; ++k) {
        const int hh = h0 + k / 3, ww = w0 + k % 3;
        const size_t pix = (size_t)(b * HH + hh) * WW + ww;
        const float* xb = x + pix * (CAPS * PS) + c * PS;
        float xt[PS];
        *(float4*)&xt[0]  = *(const float4*)xb;
        *(float4*)&xt[4]  = *(const float4*)(xb + 4);
        *(float4*)&xt[8]  = *(const float4*)(xb + 8);
        *(float4*)&xt[12] = *(const float4*)(xb + 12);
        r[k] = a[pix * CAPS + c] * (1.f / 32.f);  // initial r (it0)

        float wl[PS];
        const float* wb = wgt + k * (CAPS * PS) + c * PS;
        *(float4*)&wl[0]  = *(const float4*)wb;
        *(float4*)&wl[4]  = *(const float4*)(wb + 4);
        *(float4*)&wl[8]  = *(const float4*)(wb + 8);
        *(float4*)&wl[12] = *(const float4*)(wb + 12);

        // vote[t] = sum_q xt[(t&12)+q] * wl[q*4+(t&3)]; pair m = (2m, 2m+1)
        #pragma unroll
        for (int m = 0; m < 8; ++m) {
            f32x2 acc = splat2(0.f);
            #pragma unroll
            for (int q = 0; q < 4; ++q) {
                f32x2 w2; w2.x = wl[q * 4 + ((2 * m) & 3)]; w2.y = wl[q * 4 + ((2 * m + 1) & 3)];
                acc = pkfma(splat2(xt[((2 * m) & 12) + q]), w2, acc);
            }
            vb[k][m] = pk_f16(acc);
        }
    }

    const float bu = beta_u[c];
    const float ba = beta_a[c];
    const float eps = 1e-6f;
    const float lam = 1e-3f;

    f32x2 mu2[8], is22[8];   // is22 = 1/(2*sigma^2)
    float aoc = 0.f;
    float slgfull = 0.f;
    float r_sum;

    #pragma unroll 1   // one copy of E+M in the binary; limits live-range blowup
    for (int it = 0; it < 3; ++it) {
        if (it > 0) {
            // ---- E-step: phase-batched across the 9 independent k-chains ----
            const float addc = __logf(aoc) - slgfull - 8.f * LN_2PI;
            float lnk[PP], red[PP];
            #pragma unroll
            for (int k = 0; k < PP; ++k) {          // phase A: ln-posteriors
                f32x2 s2 = splat2(0.f);
                #pragma unroll
                for (int m = 0; m < 8; ++m) {
                    f32x2 d = unpk(vb[k][m]) - mu2[m];
                    s2 = pkfma(d * d, is22[m], s2);
                }
                lnk[k] = addc - (s2.x + s2.y);
            }
            #pragma unroll
            for (int k = 0; k < PP; ++k) red[k] = row_max16(lnk[k]);   // B: DPP maxes
            #pragma unroll
            for (int k = 0; k < PP; ++k)                                // C: swizzles
                red[k] = fmaxf(red[k], swz_xor16(red[k]));
            #pragma unroll
            for (int k = 0; k < PP; ++k) lnk[k] = __expf(lnk[k] - red[k]); // D: exps
            #pragma unroll
            for (int k = 0; k < PP; ++k) red[k] = row_sum16(lnk[k]);   // E: DPP sums
            #pragma unroll
            for (int k = 0; k < PP; ++k)                                // F: swizzles
                red[k] += swz_xor16(red[k]);
            #pragma unroll
            for (int k = 0; k < PP; ++k) r[k] = lnk[k] * frcp(red[k]); // G: normalize
        }

        // ---- M-step: two-pass (numerically required; expanded quadratic
        //      forms rejected — catastrophic cancellation class) ----
        r_sum = 0.f;
        #pragma unroll
        for (int k = 0; k < PP; ++k) r_sum += r[k];
        const float invr = frcp(r_sum + eps);
        #pragma unroll
        for (int k = 0; k < PP; ++k) r[k] *= invr;   // coeff

        #pragma unroll
        for (int m = 0; m < 8; ++m) {
            f32x2 acc = splat2(0.f);
            #pragma unroll
            for (int k = 0; k < PP; ++k) acc = pkfma(splat2(r[k]), unpk(vb[k][m]), acc);
            mu2[m] = acc;
        }
        float slg = 0.f;
        #pragma unroll
        for (int m = 0; m < 8; ++m) {
            f32x2 acc = splat2(0.f);
            #pragma unroll
            for (int k = 0; k < PP; ++k) {
                f32x2 d = unpk(vb[k][m]) - mu2[m];
                acc = pkfma(splat2(r[k]) * d, d, acc);
            }
            f32x2 sg = acc + splat2(eps);
            is22[m].x = frcp(2.f * sg.x);
            is22[m].y = frcp(2.f * sg.y);
            slg += 0.5f * __logf(sg.x * sg.y);   // = 0.5*(log sx + log sy)
        }
        slgfull = slg;
        const float ch = r_sum * (16.f * bu + slgfull);
        aoc = frcp(1.f + __expf(-lam * (ba - ch)));
    }

    // ---- outputs: each thread stores its 16 mu's (64B) + its a ----
    float* ob = out_mu + (size_t)site * (CAPS * PS) + c * PS;
    *(float4*)(ob + 0)  = *(float4*)&mu2[0];
    *(float4*)(ob + 4)  = *(float4*)&mu2[2];
    *(float4*)(ob + 8)  = *(float4*)&mu2[4];
    *(float4*)(ob + 12) = *(float4*)&mu2[6];
    out_a[(size_t)site * CAPS + c] = aoc;
}

extern "C" void kernel_launch(void* const* d_in, const int* in_sizes, int n_in,
                              void* d_out, int out_size, void* d_ws, size_t ws_size,
                              hipStream_t stream) {
    const float* x      = (const float*)d_in[0];
    const float* a      = (const float*)d_in[1];
    const float* wgt    = (const float*)d_in[2];
    const float* beta_u = (const float*)d_in[3];
    const float* beta_a = (const float*)d_in[4];

    float* out_mu = (float*)d_out;
    float* out_a  = (float*)d_out + (size_t)32 * OH * OH * CAPS * PS;  // 3,686,400

    const int n_sites = 32 * OH * OH;  // 7200
    emcaps_kernel<<<n_sites / 2, 64, 0, stream>>>(x, a, wgt, beta_u, beta_a, out_mu, out_a);
}

// Round 12
// 71.994 us; speedup vs baseline: 1.4350x; 1.0020x over previous
//
#include <hip/hip_runtime.h>
#include <math.h>

#define PP 9       // K*K
#define CAPS 32
#define PS 16
#define OH 15
#define HH 32
#define WW 32
#define LN_2PI 1.8378770664093453f

typedef float f32x2 __attribute__((ext_vector_type(2)));
typedef _Float16 f16x2 __attribute__((ext_vector_type(2)));

__device__ __forceinline__ float frcp(float x) {
    float r;
    asm("v_rcp_f32 %0, %1" : "=v"(r) : "v"(x));
    return r;
}
__device__ __forceinline__ f32x2 splat2(float x) {
    f32x2 r; r.x = x; r.y = x; return r;
}
__device__ __forceinline__ f32x2 pkfma(f32x2 a, f32x2 b, f32x2 c) {
    return __builtin_elementwise_fma(a, b, c);  // -> v_pk_fma_f32 (gfx950 packed fp32)
}

// fp16x2 vote tile (accuracy PROVEN R10/R11: absmax 0.0625 vs 0.234 thresh).
// Purpose: per-thread state small enough for 3 waves/SIMD (6 sites in flight
// vs the 4 of every 38us kernel). R11 lesson: the EM loop FITS the 170-reg
// (64,3) cap; the spill came from PHASE 1 — fully-unrolled fused load->vote
// loop let the scheduler hoist all 9 pixels' loads (144 f32 in flight on top
// of vb) -> peak ~240 regs -> allocator spilled the whole vb tile (WRITE_SIZE
// 64MB = 277B/thread = vb). Fix below: sched_barrier fences between groups
// of 3 pixels cap the transient at ~48 f32. Loop stays unrolled (static vb
// indexing — a rolled loop would force scratch).
__device__ __forceinline__ f16x2 pk_f16(f32x2 v) {
    f16x2 h;
    h.x = (_Float16)v.x;   // RNE
    h.y = (_Float16)v.y;
    return h;
}
__device__ __forceinline__ f32x2 unpk(f16x2 h) {
    f32x2 r;
    r.x = (float)h.x;
    r.y = (float)h.y;
    return r;
}

// DPP helpers (VALU pipe): quad_perm xor1=0xB1, xor2=0x4E; row_ror:4=0x124, row_ror:8=0x128.
template <int CTRL>
__device__ __forceinline__ float dppf(float x) {
    int r = __builtin_amdgcn_update_dpp(0, __builtin_bit_cast(int, x), CTRL, 0xF, 0xF, true);
    return __builtin_bit_cast(float, r);
}
__device__ __forceinline__ float row_sum16(float x) {
    x += dppf<0xB1>(x);
    x += dppf<0x4E>(x);
    x += dppf<0x124>(x);
    x += dppf<0x128>(x);
    return x;
}
__device__ __forceinline__ float row_max16(float x) {
    x = fmaxf(x, dppf<0xB1>(x));
    x = fmaxf(x, dppf<0x4E>(x));
    x = fmaxf(x, dppf<0x124>(x));
    x = fmaxf(x, dppf<0x128>(x));
    return x;
}
// xor16 within each 32-lane group (and-mask 0x1F) -> halves (= the 2 sites)
// stay independent. PROVEN primitive. permlane16_swap failed twice (R5/R6:
// identical inputs coalesce to one register -> in-place rotation). Keep this.
__device__ __forceinline__ float swz_xor16(float x) {
    return __builtin_bit_cast(float,
        __builtin_amdgcn_ds_swizzle(__builtin_bit_cast(int, x), 0x401F));
}

// Layout: each 64-lane wave = TWO sites (32 lanes each), lane = s*32 + c;
// thread owns all 16 pose elems of capsule c of site s (softmax amortized
// over 2 sites — split-PS and split-K both measured worse). Pose math packed
// f32x2 (v_pk_fma_f32); E-step phase-batched; EM loop kept rolled.
__global__ __launch_bounds__(64, 3) void emcaps_kernel(
    const float* __restrict__ x,      // (32,32,32,32,16)
    const float* __restrict__ a,      // (32,32,32,32)
    const float* __restrict__ wgt,    // (9,32,4,4)
    const float* __restrict__ beta_u, // (32)
    const float* __restrict__ beta_a, // (32)
    float* __restrict__ out_mu,       // (32,15,15,32,16)
    float* __restrict__ out_a)        // (32,15,15,32)
{
    const int lane = threadIdx.x;   // 0..63
    const int s = lane >> 5;        // site within pair
    const int c = lane & 31;        // capsule

    const int site = blockIdx.x * 2 + s;
    const int j = site % OH;
    const int t2 = site / OH;
    const int i = t2 % OH;
    const int b = t2 / OH;
    const int h0 = 2 * i, w0 = 2 * j;

    f16x2 vb[PP][8];   // fp16x2 votes: pair m = pose elems (2m, 2m+1)
    float r[PP];

    // ---- phase 1+2 fused per k: load x -> votes -> pack to fp16 ----
    // Unrolled (static vb indexing) but FENCED every 3 pixels so at most
    // 3 pixels' x-data (~48 f32) is in flight -> no register-peak spill.
    #pragma unroll
    for (int k = 0; k < PP; ++k) {
        const int hh = h0 + k / 3, ww = w0 + k % 3;
        const size_t pix = (size_t)(b * HH + hh) * WW + ww;
        const float* xb = x + pix * (CAPS * PS) + c * PS;
        float xt[PS];
        *(float4*)&xt[0]  = *(const float4*)xb;
        *(float4*)&xt[4]  = *(const float4*)(xb + 4);
        *(float4*)&xt[8]  = *(const float4*)(xb + 8);
        *(float4*)&xt[12] = *(const float4*)(xb + 12);
        r[k] = a[pix * CAPS + c] * (1.f / 32.f);  // initial r (it0)

        float wl[PS];
        const float* wb = wgt + k * (CAPS * PS) + c * PS;
        *(float4*)&wl[0]  = *(const float4*)wb;
        *(float4*)&wl[4]  = *(const float4*)(wb + 4);
        *(float4*)&wl[8]  = *(const float4*)(wb + 8);
        *(float4*)&wl[12] = *(const float4*)(wb + 12);

        // vote[t] = sum_q xt[(t&12)+q] * wl[q*4+(t&3)]; pair m = (2m, 2m+1)
        #pragma unroll
        for (int m = 0; m < 8; ++m) {
            f32x2 acc = splat2(0.f);
            #pragma unroll
            for (int q = 0; q < 4; ++q) {
                f32x2 w2; w2.x = wl[q * 4 + ((2 * m) & 3)]; w2.y = wl[q * 4 + ((2 * m + 1) & 3)];
                acc = pkfma(splat2(xt[((2 * m) & 12) + q]), w2, acc);
            }
            vb[k][m] = pk_f16(acc);
        }
        if (k == 2 || k == 5) {
            // register-pressure fence: next group's loads may not hoist
            // above this point (caps phase-1 peak at ~3 pixels in flight)
            __builtin_amdgcn_sched_barrier(0);
        }
    }

    const float bu = beta_u[c];
    const float ba = beta_a[c];
    const float eps = 1e-6f;
    const float lam = 1e-3f;

    f32x2 mu2[8], is22[8];   // is22 = 1/(2*sigma^2)
    float aoc = 0.f;
    float slgfull = 0.f;
    float r_sum;

    #pragma unroll 1   // one copy of E+M in the binary; limits live-range blowup
    for (int it = 0; it < 3; ++it) {
        if (it > 0) {
            // ---- E-step: phase-batched across the 9 independent k-chains ----
            const float addc = __logf(aoc) - slgfull - 8.f * LN_2PI;
            float lnk[PP], red[PP];
            #pragma unroll
            for (int k = 0; k < PP; ++k) {          // phase A: ln-posteriors
                f32x2 s2 = splat2(0.f);
                #pragma unroll
                for (int m = 0; m < 8; ++m) {
                    f32x2 d = unpk(vb[k][m]) - mu2[m];
                    s2 = pkfma(d * d, is22[m], s2);
                }
                lnk[k] = addc - (s2.x + s2.y);
            }
            #pragma unroll
            for (int k = 0; k < PP; ++k) red[k] = row_max16(lnk[k]);   // B: DPP maxes
            #pragma unroll
            for (int k = 0; k < PP; ++k)                                // C: swizzles
                red[k] = fmaxf(red[k], swz_xor16(red[k]));
            #pragma unroll
            for (int k = 0; k < PP; ++k) lnk[k] = __expf(lnk[k] - red[k]); // D: exps
            #pragma unroll
            for (int k = 0; k < PP; ++k) red[k] = row_sum16(lnk[k]);   // E: DPP sums
            #pragma unroll
            for (int k = 0; k < PP; ++k)                                // F: swizzles
                red[k] += swz_xor16(red[k]);
            #pragma unroll
            for (int k = 0; k < PP; ++k) r[k] = lnk[k] * frcp(red[k]); // G: normalize
        }

        // ---- M-step: two-pass (numerically required; expanded quadratic
        //      forms rejected — catastrophic cancellation class) ----
        r_sum = 0.f;
        #pragma unroll
        for (int k = 0; k < PP; ++k) r_sum += r[k];
        const float invr = frcp(r_sum + eps);
        #pragma unroll
        for (int k = 0; k < PP; ++k) r[k] *= invr;   // coeff

        #pragma unroll
        for (int m = 0; m < 8; ++m) {
            f32x2 acc = splat2(0.f);
            #pragma unroll
            for (int k = 0; k < PP; ++k) acc = pkfma(splat2(r[k]), unpk(vb[k][m]), acc);
            mu2[m] = acc;
        }
        float slg = 0.f;
        #pragma unroll
        for (int m = 0; m < 8; ++m) {
            f32x2 acc = splat2(0.f);
            #pragma unroll
            for (int k = 0; k < PP; ++k) {
                f32x2 d = unpk(vb[k][m]) - mu2[m];
                acc = pkfma(splat2(r[k]) * d, d, acc);
            }
            f32x2 sg = acc + splat2(eps);
            is22[m].x = frcp(2.f * sg.x);
            is22[m].y = frcp(2.f * sg.y);
            slg += 0.5f * __logf(sg.x * sg.y);   // = 0.5*(log sx + log sy)
        }
        slgfull = slg;
        const float ch = r_sum * (16.f * bu + slgfull);
        aoc = frcp(1.f + __expf(-lam * (ba - ch)));
    }

    // ---- outputs: each thread stores its 16 mu's (64B) + its a ----
    float* ob = out_mu + (size_t)site * (CAPS * PS) + c * PS;
    *(float4*)(ob + 0)  = *(float4*)&mu2[0];
    *(float4*)(ob + 4)  = *(float4*)&mu2[2];
    *(float4*)(ob + 8)  = *(float4*)&mu2[4];
    *(float4*)(ob + 12) = *(float4*)&mu2[6];
    out_a[(size_t)site * CAPS + c] = aoc;
}

extern "C" void kernel_launch(void* const* d_in, const int* in_sizes, int n_in,
                              void* d_out, int out_size, void* d_ws, size_t ws_size,
                              hipStream_t stream) {
    const float* x      = (const float*)d_in[0];
    const float* a      = (const float*)d_in[1];
    const float* wgt    = (const float*)d_in[2];
    const float* beta_u = (const float*)d_in[3];
    const float* beta_a = (const float*)d_in[4];

    float* out_mu = (float*)d_out;
    float* out_a  = (float*)d_out + (size_t)32 * OH * OH * CAPS * PS;  // 3,686,400

    const int n_sites = 32 * OH * OH;  // 7200
    emcaps_kernel<<<n_sites / 2, 64, 0, stream>>>(x, a, wgt, beta_u, beta_a, out_mu, out_a);
}